// Round 3
// baseline (423.469 us; speedup 1.0000x reference)
//
#include <hip/hip_runtime.h>
#include <hip/hip_bf16.h>
#include <math.h>

#define SB 8     // batch
#define SS 1024  // N == M
#define SDM 512  // model dim
#define SH 8     // heads
#define SD 64    // head dim

typedef unsigned short ushort;
typedef __attribute__((ext_vector_type(8))) short bf16x8;
typedef __attribute__((ext_vector_type(4))) float f32x4;

#define MFMA16(a, b, c) __builtin_amdgcn_mfma_f32_16x16x32_bf16(a, b, c, 0, 0, 0)

static __device__ __forceinline__ ushort f2b(float f) {
    union { float f; unsigned u; } v; v.f = f;
    unsigned r = v.u + 0x7FFF + ((v.u >> 16) & 1);   // round-nearest-even
    return (ushort)(r >> 16);
}

// async global->LDS, 16 bytes per lane (dest = wave-uniform base + lane*16)
static __device__ __forceinline__ void gll16(const void* g, void* l) {
    __builtin_amdgcn_global_load_lds(
        (const __attribute__((address_space(1))) unsigned int*)g,
        (__attribute__((address_space(3))) unsigned int*)l, 16, 0, 0);
}

// ---------------------------------------------------------------------------
// Convert inputs X (q,k,v,pos) fp32 -> bf16, 8 elems/thread. grid (2048, 4).
// ---------------------------------------------------------------------------
__global__ __launch_bounds__(256) void convert_x_kernel(
    const float* __restrict__ q, const float* __restrict__ k,
    const float* __restrict__ v, const float* __restrict__ p,
    ushort* __restrict__ xbf)
{
    const int which = blockIdx.y;
    const float* src = (which == 0) ? q : (which == 1) ? k : (which == 2) ? v : p;
    ushort* dst = xbf + (size_t)which * ((size_t)SB * SS * SDM);
    size_t i = ((size_t)blockIdx.x * 256 + threadIdx.x) * 8;
    float4 a = *(const float4*)(src + i);
    float4 b = *(const float4*)(src + i + 4);
    union { ushort u[8]; uint4 v4; } o;
    o.u[0] = f2b(a.x); o.u[1] = f2b(a.y); o.u[2] = f2b(a.z); o.u[3] = f2b(a.w);
    o.u[4] = f2b(b.x); o.u[5] = f2b(b.y); o.u[6] = f2b(b.z); o.u[7] = f2b(b.w);
    *(uint4*)(dst + i) = o.v4;
}

// ---------------------------------------------------------------------------
// Convert weights -> transposed bf16 Wt[which][col][k].
// ---------------------------------------------------------------------------
__global__ __launch_bounds__(256) void convert_w_kernel(
    const float* __restrict__ qw, const float* __restrict__ kw,
    const float* __restrict__ vw, const float* __restrict__ pw,
    const float* __restrict__ projw, ushort* __restrict__ wt)
{
    const int which = blockIdx.y;
    const int idx = blockIdx.x * 256 + threadIdx.x;
    const int c  = idx >> 9;
    const int kk = idx & 511;
    float val;
    if (which < 4) {
        const float* W = (which == 0) ? qw : (which == 1) ? kw : (which == 2) ? vw : pw;
        const int h = c >> 6, d = c & 63;
        val = W[(size_t)h * SDM * SD + (size_t)kk * SD + d];
    } else {
        val = projw[(size_t)kk * SDM + c];
    }
    wt[(size_t)which * SDM * SDM + (size_t)c * SDM + kk] = f2b(val);
}

// ---------------------------------------------------------------------------
// Kernel 1: bf16 MFMA projection GEMM, 128x128 tile.
// q_u / q_v pre-scaled by 1/sqrt(D). v written chunk-tiled: [bh][mc][d][64].
// ---------------------------------------------------------------------------
__global__ __launch_bounds__(256) void projmm_kernel(
    const ushort* __restrict__ xbf, const ushort* __restrict__ wt,
    const float* __restrict__ bias_u, const float* __restrict__ bias_v,
    ushort* __restrict__ quo, ushort* __restrict__ qvo,
    ushort* __restrict__ ko, ushort* __restrict__ po,
    ushort* __restrict__ vto)
{
    __shared__ ushort Asm[128 * 32];
    __shared__ ushort Bsm[128 * 32];

    const int tid  = threadIdx.x;
    const int wave = tid >> 6, lane = tid & 63;
    const int quad = lane >> 4, l15 = lane & 15;
    const int which = blockIdx.z;
    const int row0 = blockIdx.x * 128;
    const int col0 = blockIdx.y * 128;
    const int wr = wave >> 1, wc = wave & 1;

    const ushort* A  = xbf + (size_t)which * ((size_t)SB * SS * SDM) + (size_t)row0 * SDM;
    const ushort* Bw = wt  + (size_t)which * (SDM * SDM) + (size_t)col0 * SDM;

    f32x4 acc[4][4];
#pragma unroll
    for (int i = 0; i < 4; ++i)
#pragma unroll
        for (int j = 0; j < 4; ++j) acc[i][j] = (f32x4){0.f, 0.f, 0.f, 0.f};

    for (int k0 = 0; k0 < SDM; k0 += 32) {
#pragma unroll
        for (int j = 0; j < 2; ++j) {
            int t = j * 256 + tid;
            int r = t >> 2, kp = (t & 3) * 8;
            gll16(A  + (size_t)r * SDM + k0 + kp, (char*)Asm + t * 16);
            gll16(Bw + (size_t)r * SDM + k0 + kp, (char*)Bsm + t * 16);
        }
        __syncthreads();

        bf16x8 af[4], bfr[4];
#pragma unroll
        for (int mt = 0; mt < 4; ++mt)
            af[mt] = *(const bf16x8*)&Asm[(wr * 64 + mt * 16 + l15) * 32 + quad * 8];
#pragma unroll
        for (int nt = 0; nt < 4; ++nt)
            bfr[nt] = *(const bf16x8*)&Bsm[(wc * 64 + nt * 16 + l15) * 32 + quad * 8];
#pragma unroll
        for (int mt = 0; mt < 4; ++mt)
#pragma unroll
            for (int nt = 0; nt < 4; ++nt)
                acc[mt][nt] = MFMA16(af[mt], bfr[nt], acc[mt][nt]);
        __syncthreads();
    }

    const float SC = 0.125f;   // 1/sqrt(D) folded into q
#pragma unroll
    for (int nt = 0; nt < 4; ++nt) {
        const int C = col0 + wc * 64 + nt * 16 + l15;
        const int h = C >> 6, d = C & 63;
        if (which == 0) {
            const float bu = bias_u[C];
            const float bv = bias_v[C];
#pragma unroll
            for (int mt = 0; mt < 4; ++mt) {
                const int Rb = row0 + wr * 64 + mt * 16 + quad * 4;
                const int b = Rb >> 10;
                const int n = Rb & 1023;
                const size_t base = ((size_t)(b * SH + h) * SS + n) * SD + d;
#pragma unroll
                for (int r = 0; r < 4; ++r) {
                    quo[base + (size_t)r * SD] = f2b((acc[mt][nt][r] + bu) * SC);
                    qvo[base + (size_t)r * SD] = f2b((acc[mt][nt][r] + bv) * SC);
                }
            }
        } else if (which == 1 || which == 3) {
            ushort* out = (which == 1) ? ko : po;
#pragma unroll
            for (int mt = 0; mt < 4; ++mt) {
                const int Rb = row0 + wr * 64 + mt * 16 + quad * 4;
                const int b = Rb >> 10;
                const int n = Rb & 1023;
                const size_t base = ((size_t)(b * SH + h) * SS + n) * SD + d;
#pragma unroll
                for (int r = 0; r < 4; ++r)
                    out[base + (size_t)r * SD] = f2b(acc[mt][nt][r]);
            }
        } else {
            // v chunk-tiled: vto[bh][n>>6][d][64]
#pragma unroll
            for (int mt = 0; mt < 4; ++mt) {
                const int Rb = row0 + wr * 64 + mt * 16 + quad * 4;
                const int b = Rb >> 10;
                const int n = Rb & 1023;
                union { ushort u[4]; uint2 v2; } pk;
#pragma unroll
                for (int r = 0; r < 4; ++r) pk.u[r] = f2b(acc[mt][nt][r]);
                const size_t base = (size_t)(b * SH + h) * SS * SD
                                  + ((size_t)((n >> 6) * 64 + d)) * 64 + (n & 63);
                *(uint2*)&vto[base] = pk.v2;
            }
        }
    }
}

// ---------------------------------------------------------------------------
// Kernel 2: bf16 MFMA attention, ZERO-STAGING / ZERO-BARRIER main loop.
// Per (b,h): k + p + v = 384 KB, L2-resident; all 16 n-tile blocks of a
// (b,h) pinned to one XCD by the grid swizzle, so k/p/v fragment reads are
// direct global loads (L2 hits) in the same 16-rows-x-64B pattern v already
// used. No Kb/Pb LDS, no global_load_lds, no __syncthreads in the loop ->
// waves are fully independent (latency hidden by 16+ waves/CU slipping
// freely instead of lock-step barriers draining vmcnt(0) 32x/block).
// Relative-shift diagonal gather: parallel band GEMM into wave-private
// Glds [16][81] f32 (pad 80->81 kills the 4-quad write aliasing:
// old stride 320 B = 0 mod 128 B), then 16 gather reads. No serial
// shuffle chains (round-2's streamed __shfl gather was slower: each tile
// was MFMA -> ds_bpermute(120cy) -> select, a dependent chain).
// LDS total ~30 KB (all wave-private). No forced launch bound (a forced
// waves-per-eu of 4 capped VGPR at 64 -> spills -> 205 MB scratch traffic).
// ---------------------------------------------------------------------------
__global__ __launch_bounds__(256) void attn_kernel(
    const ushort* __restrict__ qu, const ushort* __restrict__ qv,
    const ushort* __restrict__ kk, const ushort* __restrict__ pp,
    const ushort* __restrict__ vt, ushort* __restrict__ ctx)
{
    __shared__ float  Glds[4][16][81];   // 20.7 KB band gather scratch (wave-private)
    __shared__ ushort Plds[4][16][72];   //  9 KB P C->A transform (wave-private)

    const int tid  = threadIdx.x;
    const int wave = tid >> 6;
    const int lane = tid & 63;
    const int quad = lane >> 4;
    const int l15  = lane & 15;

    const int id   = blockIdx.x;
    const int xcd  = id & 7;
    const int slot = id >> 3;               // 0..127
    const int bhid = xcd * 8 + (slot >> 4); // 0..63
    const int nt   = slot & 15;
    const int b    = bhid >> 3;
    const int h    = bhid & 7;
    const int n0   = nt * 64;

    const size_t bh   = (size_t)(b * SH + h);
    const ushort* qu_bh = qu + bh * SS * SD;
    const ushort* qv_bh = qv + bh * SS * SD;
    const ushort* k_bh  = kk + bh * SS * SD;
    const ushort* p_bh  = pp + bh * SS * SD;
    const ushort* vt_bh = vt + bh * SS * SD;   // chunk-tiled [mc][d][64]

    const int mcD = n0 >> 6;   // diagonal chunk index

    const int arow  = n0 + wave * 16 + l15;
    const int arow2 = (arow + 1 < SS) ? arow + 1 : SS - 1;

    bf16x8 a_u0  = *(const bf16x8*)(qu_bh + (size_t)arow  * SD + quad * 8);
    bf16x8 a_u1  = *(const bf16x8*)(qu_bh + (size_t)arow  * SD + quad * 8 + 32);
    bf16x8 a_vl0 = *(const bf16x8*)(qv_bh + (size_t)arow  * SD + quad * 8);
    bf16x8 a_vl1 = *(const bf16x8*)(qv_bh + (size_t)arow  * SD + quad * 8 + 32);
    bf16x8 a_vu0 = *(const bf16x8*)(qv_bh + (size_t)arow2 * SD + quad * 8);
    bf16x8 a_vu1 = *(const bf16x8*)(qv_bh + (size_t)arow2 * SD + quad * 8 + 32);

    float lsum[4] = {0.f, 0.f, 0.f, 0.f};
    f32x4 O[4];
#pragma unroll
    for (int dt = 0; dt < 4; ++dt) O[dt] = (f32x4){0.f, 0.f, 0.f, 0.f};

    float  (*Gl)[81] = Glds[wave];
    ushort (*Pl)[72] = Plds[wave];

    for (int mc = 0; mc < 16; ++mc) {
        const int m0 = mc * 64;
        const int diff = m0 - n0;
        const bool lowerband = (mc <= mcD);

        // ---- S_u = q_u . k^T, k fragments direct from global (L2) ----
        f32x4 S[4];
#pragma unroll
        for (int mt = 0; mt < 4; ++mt) {
            const ushort* kr = k_bh + (size_t)(m0 + mt * 16 + l15) * SD + quad * 8;
            f32x4 c = (f32x4){0.f, 0.f, 0.f, 0.f};
            c = MFMA16(a_u0, *(const bf16x8*)kr, c);
            c = MFMA16(a_u1, *(const bf16x8*)(kr + 32), c);
            S[mt] = c;
        }

        // ---- band GEMM (p direct from global) -> Glds -> diagonal gather ----
        float sv[4][4];
        {
            const bf16x8 av0 = lowerband ? a_vl0 : a_vu0;
            const bf16x8 av1 = lowerband ? a_vl1 : a_vu1;
            const int cb = lowerband ? (diff + 960) : (diff - 65);
#pragma unroll
            for (int ti = 0; ti < 5; ++ti) {
                const int t = (3 - wave + ti) * 16 + l15;
                int c = cb + t; c = (c < 0) ? 0 : (c > SS - 1 ? SS - 1 : c);
                const ushort* pr = p_bh + (size_t)c * SD + quad * 8;
                f32x4 g = (f32x4){0.f, 0.f, 0.f, 0.f};
                g = MFMA16(av0, *(const bf16x8*)pr, g);
                g = MFMA16(av1, *(const bf16x8*)(pr + 32), g);
#pragma unroll
                for (int r = 0; r < 4; ++r)
                    Gl[quad * 4 + r][ti * 16 + l15] = g[r];
            }
#pragma unroll
            for (int mt = 0; mt < 4; ++mt) {
                const int mloc = mt * 16 + l15;
#pragma unroll
                for (int r = 0; r < 4; ++r) {
                    const int q4r = quad * 4 + r;
                    const int d1 = diff + mloc - (wave * 16 + q4r);
                    const bool use = lowerband ? (d1 <= 0) : (d1 >= 2);
                    sv[mt][r] = use ? Gl[q4r][mloc - q4r + 15] : 0.f;
                }
            }
        }

        // ---- diagonal chunk: upper band, same path ----
        if (mc == mcD) {
            const int cbase = diff - 65;
#pragma unroll
            for (int ti = 0; ti < 5; ++ti) {
                const int t = (3 - wave + ti) * 16 + l15;
                int c = cbase + t; c = (c < 0) ? 0 : (c > SS - 1 ? SS - 1 : c);
                const ushort* pr = p_bh + (size_t)c * SD + quad * 8;
                f32x4 g = (f32x4){0.f, 0.f, 0.f, 0.f};
                g = MFMA16(a_vu0, *(const bf16x8*)pr, g);
                g = MFMA16(a_vu1, *(const bf16x8*)(pr + 32), g);
#pragma unroll
                for (int r = 0; r < 4; ++r)
                    Gl[quad * 4 + r][ti * 16 + l15] = g[r];
            }
#pragma unroll
            for (int mt = 0; mt < 4; ++mt) {
                const int mloc = mt * 16 + l15;
#pragma unroll
                for (int r = 0; r < 4; ++r) {
                    const int q4r = quad * 4 + r;
                    const int d1 = diff + mloc - (wave * 16 + q4r);
                    if (d1 >= 2) sv[mt][r] = Gl[q4r][mloc - q4r + 15];
                }
            }
        }

        // ---- v burst (direct, line-aligned chunk-tiled rows) ----
        bf16x8 vb0[4], vb1[4];
#pragma unroll
        for (int dt = 0; dt < 4; ++dt) {
            const ushort* vp = vt_bh + (size_t)(m0 + dt * 16 + l15) * 64 + quad * 8;
            vb0[dt] = *(const bf16x8*)vp;
            vb1[dt] = *(const bf16x8*)(vp + 32);
        }

        // ---- e = exp(logit), lane-local l accumulation ----
        float e[4][4];
#pragma unroll
        for (int mt = 0; mt < 4; ++mt)
#pragma unroll
            for (int r = 0; r < 4; ++r) {
                e[mt][r] = __expf(S[mt][r] + sv[mt][r]);
                lsum[r] += e[mt][r];
            }

        // ---- P: C-layout -> A-layout via wave-private LDS ----
#pragma unroll
        for (int mt = 0; mt < 4; ++mt)
#pragma unroll
            for (int r = 0; r < 4; ++r)
                Pl[quad * 4 + r][mt * 16 + l15] = f2b(e[mt][r]);

        // ---- O += P . V ----
        bf16x8 ap0 = *(const bf16x8*)&Pl[l15][quad * 8];
        bf16x8 ap1 = *(const bf16x8*)&Pl[l15][32 + quad * 8];
#pragma unroll
        for (int dt = 0; dt < 4; ++dt) {
            O[dt] = MFMA16(ap0, vb0[dt], O[dt]);
            O[dt] = MFMA16(ap1, vb1[dt], O[dt]);
        }
    }

    // final l reduction across the 16 lanes of each row group
#pragma unroll
    for (int mask = 1; mask <= 8; mask <<= 1)
#pragma unroll
        for (int r = 0; r < 4; ++r)
            lsum[r] += __shfl_xor(lsum[r], mask, 16);

    float inv[4];
#pragma unroll
    for (int r = 0; r < 4; ++r) inv[r] = 1.f / lsum[r];

#pragma unroll
    for (int dt = 0; dt < 4; ++dt)
#pragma unroll
        for (int r = 0; r < 4; ++r) {
            int nn = n0 + wave * 16 + quad * 4 + r;
            ctx[((size_t)b * SS + nn) * (SH * SD) + h * SD + dt * 16 + l15] =
                f2b(O[dt][r] * inv[r]);
        }
}

// ---------------------------------------------------------------------------
// Kernel 3: output projection, bf16 MFMA GEMM.
// ---------------------------------------------------------------------------
__global__ __launch_bounds__(256) void outproj_kernel(
    const ushort* __restrict__ ctx, const ushort* __restrict__ wt,
    float* __restrict__ out)
{
    __shared__ ushort Asm[128 * 32];
    __shared__ ushort Bsm[128 * 32];

    const int tid  = threadIdx.x;
    const int wave = tid >> 6, lane = tid & 63;
    const int quad = lane >> 4, l15 = lane & 15;
    const int row0 = blockIdx.x * 128;
    const int col0 = blockIdx.y * 128;
    const int wr = wave >> 1, wc = wave & 1;

    const ushort* A  = ctx + (size_t)row0 * SDM;
    const ushort* Bw = wt + (size_t)4 * (SDM * SDM) + (size_t)col0 * SDM;

    f32x4 acc[4][4];
#pragma unroll
    for (int i = 0; i < 4; ++i)
#pragma unroll
        for (int j = 0; j < 4; ++j) acc[i][j] = (f32x4){0.f, 0.f, 0.f, 0.f};

    for (int k0 = 0; k0 < SDM; k0 += 32) {
#pragma unroll
        for (int j = 0; j < 2; ++j) {
            int t = j * 256 + tid;
            int r = t >> 2, kp = (t & 3) * 8;
            gll16(A  + (size_t)r * SDM + k0 + kp, (char*)Asm + t * 16);
            gll16(Bw + (size_t)r * SDM + k0 + kp, (char*)Bsm + t * 16);
        }
        __syncthreads();

        bf16x8 af[4], bfr[4];
#pragma unroll
        for (int mt = 0; mt < 4; ++mt)
            af[mt] = *(const bf16x8*)&Asm[(wr * 64 + mt * 16 + l15) * 32 + quad * 8];
#pragma unroll
        for (int nt = 0; nt < 4; ++nt)
            bfr[nt] = *(const bf16x8*)&Bsm[(wc * 64 + nt * 16 + l15) * 32 + quad * 8];
#pragma unroll
        for (int mt = 0; mt < 4; ++mt)
#pragma unroll
            for (int nt = 0; nt < 4; ++nt)
                acc[mt][nt] = MFMA16(af[mt], bfr[nt], acc[mt][nt]);
        __syncthreads();
    }

#pragma unroll
    for (int mt = 0; mt < 4; ++mt)
#pragma unroll
        for (int nt = 0; nt < 4; ++nt) {
            const int R = row0 + wr * 64 + mt * 16 + quad * 4;
            const int C = col0 + wc * 64 + nt * 16 + l15;
#pragma unroll
            for (int r = 0; r < 4; ++r)
                out[(size_t)(R + r) * SDM + C] = acc[mt][nt][r];
        }
}

// ---------------------------------------------------------------------------
extern "C" void kernel_launch(void* const* d_in, const int* in_sizes, int n_in,
                              void* d_out, int out_size, void* d_ws, size_t ws_size,
                              hipStream_t stream)
{
    const float* query  = (const float*)d_in[0];
    const float* key    = (const float*)d_in[1];
    const float* value  = (const float*)d_in[2];
    const float* pos    = (const float*)d_in[3];
    const float* qw     = (const float*)d_in[4];
    const float* kw     = (const float*)d_in[5];
    const float* vw     = (const float*)d_in[6];
    const float* pw     = (const float*)d_in[7];
    const float* projw  = (const float*)d_in[8];
    const float* bias_u = (const float*)d_in[9];
    const float* bias_v = (const float*)d_in[10];

    char* w = (char*)d_ws;
    const size_t MB = 1024 * 1024;
    ushort* xbf = (ushort*)w;                 // 32 MB (dead after projmm)
    ushort* quo = (ushort*)(w + 32 * MB);
    ushort* qvo = (ushort*)(w + 40 * MB);
    ushort* ko  = (ushort*)(w + 48 * MB);
    ushort* po  = (ushort*)(w + 56 * MB);
    ushort* vto = (ushort*)(w + 64 * MB);     // chunk-tiled [bh][mc][d][64]
    ushort* wt  = (ushort*)(w + 72 * MB);     // 2.5 MB
    ushort* ctx = (ushort*)w;                 // aliases dead xbf

    dim3 gcx(2048, 4);
    convert_x_kernel<<<gcx, 256, 0, stream>>>(query, key, value, pos, xbf);
    dim3 gcw(1024, 5);
    convert_w_kernel<<<gcw, 256, 0, stream>>>(qw, kw, vw, pw, projw, wt);

    dim3 g1(64, 4, 4);
    projmm_kernel<<<g1, 256, 0, stream>>>(xbf, wt, bias_u, bias_v,
                                          quo, qvo, ko, po, vto);

    attn_kernel<<<dim3(1024), 256, 0, stream>>>(quo, qvo, ko, po, vto, ctx);

    dim3 g3(64, 4);
    outproj_kernel<<<g3, 256, 0, stream>>>(ctx, wt, (float*)d_out);
}

// Round 6
// 376.707 us; speedup vs baseline: 1.1241x; 1.1241x over previous
//
#include <hip/hip_runtime.h>
#include <hip/hip_bf16.h>
#include <math.h>

#define SB 8     // batch
#define SS 1024  // N == M
#define SDM 512  // model dim
#define SH 8     // heads
#define SD 64    // head dim

typedef unsigned short ushort;
typedef __attribute__((ext_vector_type(8))) short bf16x8;
typedef __attribute__((ext_vector_type(4))) float f32x4;

#define MFMA16(a, b, c) __builtin_amdgcn_mfma_f32_16x16x32_bf16(a, b, c, 0, 0, 0)

static __device__ __forceinline__ ushort f2b(float f) {
    union { float f; unsigned u; } v; v.f = f;
    unsigned r = v.u + 0x7FFF + ((v.u >> 16) & 1);   // round-nearest-even
    return (ushort)(r >> 16);
}

// async global->LDS, 16 bytes per lane (dest = wave-uniform base + lane*16)
static __device__ __forceinline__ void gll16(const void* g, void* l) {
    __builtin_amdgcn_global_load_lds(
        (const __attribute__((address_space(1))) unsigned int*)g,
        (__attribute__((address_space(3))) unsigned int*)l, 16, 0, 0);
}

// ---------------------------------------------------------------------------
// Convert inputs X (q,k,v,pos) fp32 -> bf16, 8 elems/thread. grid (2048, 4).
// ---------------------------------------------------------------------------
__global__ __launch_bounds__(256) void convert_x_kernel(
    const float* __restrict__ q, const float* __restrict__ k,
    const float* __restrict__ v, const float* __restrict__ p,
    ushort* __restrict__ xbf)
{
    const int which = blockIdx.y;
    const float* src = (which == 0) ? q : (which == 1) ? k : (which == 2) ? v : p;
    ushort* dst = xbf + (size_t)which * ((size_t)SB * SS * SDM);
    size_t i = ((size_t)blockIdx.x * 256 + threadIdx.x) * 8;
    float4 a = *(const float4*)(src + i);
    float4 b = *(const float4*)(src + i + 4);
    union { ushort u[8]; uint4 v4; } o;
    o.u[0] = f2b(a.x); o.u[1] = f2b(a.y); o.u[2] = f2b(a.z); o.u[3] = f2b(a.w);
    o.u[4] = f2b(b.x); o.u[5] = f2b(b.y); o.u[6] = f2b(b.z); o.u[7] = f2b(b.w);
    *(uint4*)(dst + i) = o.v4;
}

// ---------------------------------------------------------------------------
// Convert weights -> transposed bf16 Wt[which][col][k].
// ---------------------------------------------------------------------------
__global__ __launch_bounds__(256) void convert_w_kernel(
    const float* __restrict__ qw, const float* __restrict__ kw,
    const float* __restrict__ vw, const float* __restrict__ pw,
    const float* __restrict__ projw, ushort* __restrict__ wt)
{
    const int which = blockIdx.y;
    const int idx = blockIdx.x * 256 + threadIdx.x;
    const int c  = idx >> 9;
    const int kk = idx & 511;
    float val;
    if (which < 4) {
        const float* W = (which == 0) ? qw : (which == 1) ? kw : (which == 2) ? vw : pw;
        const int h = c >> 6, d = c & 63;
        val = W[(size_t)h * SDM * SD + (size_t)kk * SD + d];
    } else {
        val = projw[(size_t)kk * SDM + c];
    }
    wt[(size_t)which * SDM * SDM + (size_t)c * SDM + kk] = f2b(val);
}

// ---------------------------------------------------------------------------
// Kernel 1: bf16 MFMA projection GEMM, 128x128 tile.
// q_u / q_v pre-scaled by 1/sqrt(D). v written chunk-tiled: [bh][mc][d][64].
// ---------------------------------------------------------------------------
__global__ __launch_bounds__(256) void projmm_kernel(
    const ushort* __restrict__ xbf, const ushort* __restrict__ wt,
    const float* __restrict__ bias_u, const float* __restrict__ bias_v,
    ushort* __restrict__ quo, ushort* __restrict__ qvo,
    ushort* __restrict__ ko, ushort* __restrict__ po,
    ushort* __restrict__ vto)
{
    __shared__ ushort Asm[128 * 32];
    __shared__ ushort Bsm[128 * 32];

    const int tid  = threadIdx.x;
    const int wave = tid >> 6, lane = tid & 63;
    const int quad = lane >> 4, l15 = lane & 15;
    const int which = blockIdx.z;
    const int row0 = blockIdx.x * 128;
    const int col0 = blockIdx.y * 128;
    const int wr = wave >> 1, wc = wave & 1;

    const ushort* A  = xbf + (size_t)which * ((size_t)SB * SS * SDM) + (size_t)row0 * SDM;
    const ushort* Bw = wt  + (size_t)which * (SDM * SDM) + (size_t)col0 * SDM;

    f32x4 acc[4][4];
#pragma unroll
    for (int i = 0; i < 4; ++i)
#pragma unroll
        for (int j = 0; j < 4; ++j) acc[i][j] = (f32x4){0.f, 0.f, 0.f, 0.f};

    for (int k0 = 0; k0 < SDM; k0 += 32) {
#pragma unroll
        for (int j = 0; j < 2; ++j) {
            int t = j * 256 + tid;
            int r = t >> 2, kp = (t & 3) * 8;
            gll16(A  + (size_t)r * SDM + k0 + kp, (char*)Asm + t * 16);
            gll16(Bw + (size_t)r * SDM + k0 + kp, (char*)Bsm + t * 16);
        }
        __syncthreads();

        bf16x8 af[4], bfr[4];
#pragma unroll
        for (int mt = 0; mt < 4; ++mt)
            af[mt] = *(const bf16x8*)&Asm[(wr * 64 + mt * 16 + l15) * 32 + quad * 8];
#pragma unroll
        for (int nt = 0; nt < 4; ++nt)
            bfr[nt] = *(const bf16x8*)&Bsm[(wc * 64 + nt * 16 + l15) * 32 + quad * 8];
#pragma unroll
        for (int mt = 0; mt < 4; ++mt)
#pragma unroll
            for (int nt = 0; nt < 4; ++nt)
                acc[mt][nt] = MFMA16(af[mt], bfr[nt], acc[mt][nt]);
        __syncthreads();
    }

    const float SC = 0.125f;   // 1/sqrt(D) folded into q
#pragma unroll
    for (int nt = 0; nt < 4; ++nt) {
        const int C = col0 + wc * 64 + nt * 16 + l15;
        const int h = C >> 6, d = C & 63;
        if (which == 0) {
            const float bu = bias_u[C];
            const float bv = bias_v[C];
#pragma unroll
            for (int mt = 0; mt < 4; ++mt) {
                const int Rb = row0 + wr * 64 + mt * 16 + quad * 4;
                const int b = Rb >> 10;
                const int n = Rb & 1023;
                const size_t base = ((size_t)(b * SH + h) * SS + n) * SD + d;
#pragma unroll
                for (int r = 0; r < 4; ++r) {
                    quo[base + (size_t)r * SD] = f2b((acc[mt][nt][r] + bu) * SC);
                    qvo[base + (size_t)r * SD] = f2b((acc[mt][nt][r] + bv) * SC);
                }
            }
        } else if (which == 1 || which == 3) {
            ushort* out = (which == 1) ? ko : po;
#pragma unroll
            for (int mt = 0; mt < 4; ++mt) {
                const int Rb = row0 + wr * 64 + mt * 16 + quad * 4;
                const int b = Rb >> 10;
                const int n = Rb & 1023;
                const size_t base = ((size_t)(b * SH + h) * SS + n) * SD + d;
#pragma unroll
                for (int r = 0; r < 4; ++r)
                    out[base + (size_t)r * SD] = f2b(acc[mt][nt][r]);
            }
        } else {
            // v chunk-tiled: vto[bh][n>>6][d][64]
#pragma unroll
            for (int mt = 0; mt < 4; ++mt) {
                const int Rb = row0 + wr * 64 + mt * 16 + quad * 4;
                const int b = Rb >> 10;
                const int n = Rb & 1023;
                union { ushort u[4]; uint2 v2; } pk;
#pragma unroll
                for (int r = 0; r < 4; ++r) pk.u[r] = f2b(acc[mt][nt][r]);
                const size_t base = (size_t)(b * SH + h) * SS * SD
                                  + ((size_t)((n >> 6) * 64 + d)) * 64 + (n & 63);
                *(uint2*)&vto[base] = pk.v2;
            }
        }
    }
}

// XOR-swizzled LDS fragment read: 16B segment `seg` of logical row `row`
// (row stride 64 ushorts = 128 B; store placed seg at slot seg^(row&7)).
static __device__ __forceinline__ bf16x8 sfrag(const ushort* buf, int row, int seg) {
    return *(const bf16x8*)&buf[(size_t)row * 64 + ((seg ^ (row & 7)) * 8)];
}

// ---------------------------------------------------------------------------
// Kernel 2: bf16 MFMA attention. Round-0 staged skeleton (Kb/Pb via
// global_load_lds + barriers; stage(mc+1) issued before exp/PV to overlap
// DMA) + PARALLEL in-register diagonal gather: all 5 band tiles g[0..4]
// computed first, then 20 INDEPENDENT __shfl (ds_bpermute, pipelined,
// conflict-free) + constant-index selects (all array indices compile-time
// after unroll -> registers, not scratch). This removes round-0's 20.7 KB
// Glds round-trip whose gather read was a structural 4-way bank conflict
// (bank independent of quad: 5.43 M conflict cycles), and avoids round-2's
// serial MFMA->shfl->select chain (streamed variant, 118 us). Round-1 had
// this structure but was spilled to death by a forced waves-per-EU bound
// (VGPR capped 64 -> 205 MB scratch traffic): natural allocation only.
// LDS = 33.8 KB -> 4 blocks/CU. v fragments loaded before the shuffle
// phase so their L2 latency hides under gather/select work.
// XCD-clustered grid (1024): all 16 n-tiles of a (b,h) share an XCD L2.
// ---------------------------------------------------------------------------
__global__ __launch_bounds__(256) void attn_kernel(
    const ushort* __restrict__ qu, const ushort* __restrict__ qv,
    const ushort* __restrict__ kk, const ushort* __restrict__ pp,
    const ushort* __restrict__ vt, ushort* __restrict__ ctx)
{
    __shared__ ushort Kb[64 * 64];       //  8 KB staged k chunk
    __shared__ ushort Pb[128 * 64];      // 16 KB staged p band
    __shared__ ushort Plds[4][16][72];   //  9 KB P C->A transform (wave-private)

    const int tid  = threadIdx.x;
    const int wave = tid >> 6;
    const int lane = tid & 63;
    const int quad = lane >> 4;
    const int l15  = lane & 15;

    const int id   = blockIdx.x;
    const int xcd  = id & 7;
    const int slot = id >> 3;               // 0..127
    const int bhid = xcd * 8 + (slot >> 4); // 0..63
    const int nt   = slot & 15;
    const int b    = bhid >> 3;
    const int h    = bhid & 7;
    const int n0   = nt * 64;

    const size_t bh   = (size_t)(b * SH + h);
    const ushort* qu_bh = qu + bh * SS * SD;
    const ushort* qv_bh = qv + bh * SS * SD;
    const ushort* k_bh  = kk + bh * SS * SD;
    const ushort* p_bh  = pp + bh * SS * SD;
    const ushort* vt_bh = vt + bh * SS * SD;   // chunk-tiled [mc][d][64]

    const int mcD = n0 >> 6;   // diagonal chunk index

    const int arow  = n0 + wave * 16 + l15;
    const int arow2 = (arow + 1 < SS) ? arow + 1 : SS - 1;

    bf16x8 a_u0  = *(const bf16x8*)(qu_bh + (size_t)arow  * SD + quad * 8);
    bf16x8 a_u1  = *(const bf16x8*)(qu_bh + (size_t)arow  * SD + quad * 8 + 32);
    bf16x8 a_vl0 = *(const bf16x8*)(qv_bh + (size_t)arow  * SD + quad * 8);
    bf16x8 a_vl1 = *(const bf16x8*)(qv_bh + (size_t)arow  * SD + quad * 8 + 32);
    bf16x8 a_vu0 = *(const bf16x8*)(qv_bh + (size_t)arow2 * SD + quad * 8);
    bf16x8 a_vu1 = *(const bf16x8*)(qv_bh + (size_t)arow2 * SD + quad * 8 + 32);

    // per-lane constant shuffle pattern for the diagonal gather:
    // value for (quad,l15,r,mt) comes from lane (lane&48)|(o&15) of tile
    // g[mt + (o>=16)], o = l15+15-quad*4-r  (verified rounds 1-2)
    int gsrc[4]; bool ghi[4];
#pragma unroll
    for (int r = 0; r < 4; ++r) {
        const int o = l15 + 15 - quad * 4 - r;
        gsrc[r] = (lane & 48) | (o & 15);
        ghi[r]  = (o >= 16);
    }

    float lsum[4] = {0.f, 0.f, 0.f, 0.f};
    f32x4 O[4];
#pragma unroll
    for (int dt = 0; dt < 4; ++dt) O[dt] = (f32x4){0.f, 0.f, 0.f, 0.f};

    ushort (*Pl)[72] = Plds[wave];

    // stage chunk mc's k (64 rows) + p band (128 rows) into LDS, XOR-swizzled
    auto stage = [&](int mc) {
        const int m0s = mc * 64;
        const int cb  = (mc <= mcD) ? (m0s - n0 + 960) : (m0s - n0 - 65);
#pragma unroll
        for (int it = 0; it < 2; ++it) {
            int t = it * 256 + tid;
            int r = t >> 3, s = t & 7;
            gll16(k_bh + (size_t)(m0s + r) * 64 + ((s ^ (r & 7)) * 8),
                  (char*)Kb + t * 16);
        }
#pragma unroll
        for (int it = 0; it < 4; ++it) {
            int t = it * 256 + tid;
            int r = t >> 3, s = t & 7;
            int c = cb + r; c = (c < 0) ? 0 : (c > SS - 1 ? SS - 1 : c);
            gll16(p_bh + (size_t)c * 64 + ((s ^ (r & 7)) * 8),
                  (char*)Pb + t * 16);
        }
    };

    stage(0);

    for (int mc = 0; mc < 16; ++mc) {
        const int m0 = mc * 64;
        const int diff = m0 - n0;
        const bool lowerband = (mc <= mcD);

        __syncthreads();   // staged data ready (compiler drains vmcnt before barrier)

        // ---- S_u = q_u . k^T from staged Kb ----
        f32x4 S[4];
#pragma unroll
        for (int mt = 0; mt < 4; ++mt) {
            const int r = mt * 16 + l15;
            f32x4 c = (f32x4){0.f, 0.f, 0.f, 0.f};
            c = MFMA16(a_u0, sfrag(Kb, r, quad), c);
            c = MFMA16(a_u1, sfrag(Kb, r, quad + 4), c);
            S[mt] = c;
        }

        // ---- band GEMM from staged Pb: all 5 tiles up front ----
        f32x4 g[5];
        {
            const bf16x8 av0 = lowerband ? a_vl0 : a_vu0;
            const bf16x8 av1 = lowerband ? a_vl1 : a_vu1;
#pragma unroll
            for (int ti = 0; ti < 5; ++ti) {
                const int t = (3 - wave + ti) * 16 + l15;
                f32x4 gg = (f32x4){0.f, 0.f, 0.f, 0.f};
                gg = MFMA16(av0, sfrag(Pb, t, quad), gg);
                gg = MFMA16(av1, sfrag(Pb, t, quad + 4), gg);
                g[ti] = gg;
            }
        }

        // ---- v burst issued now: L2 latency hides under shuffle/select ----
        bf16x8 vb0[4], vb1[4];
#pragma unroll
        for (int dt = 0; dt < 4; ++dt) {
            const ushort* vp = vt_bh + (size_t)(m0 + dt * 16 + l15) * 64 + quad * 8;
            vb0[dt] = *(const bf16x8*)vp;
            vb1[dt] = *(const bf16x8*)(vp + 32);
        }

        // ---- parallel in-register diagonal gather (20 independent shfl) ----
        float sv[4][4];
        {
            const int dbase = diff + l15 - wave * 16 - quad * 4; // d1 = dbase+16mt-r
#pragma unroll
            for (int r = 0; r < 4; ++r) {
                float hh[5];
#pragma unroll
                for (int ti = 0; ti < 5; ++ti)
                    hh[ti] = __shfl(g[ti][r], gsrc[r]);
                const int d1b = dbase - r;
#pragma unroll
                for (int mt = 0; mt < 4; ++mt) {
                    const float v = ghi[r] ? hh[mt + 1] : hh[mt];
                    const int d1 = d1b + 16 * mt;
                    const bool use = lowerband ? (d1 <= 0) : (d1 >= 2);
                    sv[mt][r] = use ? v : 0.f;
                }
            }
        }

        // ---- diagonal chunk: upper band direct from global, same gather ----
        if (mc == mcD) {
            const int cbase = diff - 65;
            f32x4 gd[5];
#pragma unroll
            for (int ti = 0; ti < 5; ++ti) {
                int c = cbase + (3 - wave + ti) * 16 + l15;
                c = (c < 0) ? 0 : (c > SS - 1 ? SS - 1 : c);
                const ushort* pr = p_bh + (size_t)c * SD + quad * 8;
                f32x4 gg = (f32x4){0.f, 0.f, 0.f, 0.f};
                gg = MFMA16(a_vu0, *(const bf16x8*)pr, gg);
                gg = MFMA16(a_vu1, *(const bf16x8*)(pr + 32), gg);
                gd[ti] = gg;
            }
            const int dbase = diff + l15 - wave * 16 - quad * 4;
#pragma unroll
            for (int r = 0; r < 4; ++r) {
                float hh[5];
#pragma unroll
                for (int ti = 0; ti < 5; ++ti)
                    hh[ti] = __shfl(gd[ti][r], gsrc[r]);
                const int d1b = dbase - r;
#pragma unroll
                for (int mt = 0; mt < 4; ++mt) {
                    const float v = ghi[r] ? hh[mt + 1] : hh[mt];
                    if (d1b + 16 * mt >= 2) sv[mt][r] = v;
                }
            }
        }

        __syncthreads();   // all waves done reading Kb/Pb
        if (mc + 1 < 16) stage(mc + 1);   // DMA overlaps exp/PV below

        // ---- e = exp(logit), lane-local l accumulation ----
        float e[4][4];
#pragma unroll
        for (int mt = 0; mt < 4; ++mt)
#pragma unroll
            for (int r = 0; r < 4; ++r) {
                e[mt][r] = __expf(S[mt][r] + sv[mt][r]);
                lsum[r] += e[mt][r];
            }

        // ---- P: C-layout -> A-layout via wave-private LDS ----
#pragma unroll
        for (int mt = 0; mt < 4; ++mt)
#pragma unroll
            for (int r = 0; r < 4; ++r)
                Pl[quad * 4 + r][mt * 16 + l15] = f2b(e[mt][r]);

        // ---- O += P . V ----
        bf16x8 ap0 = *(const bf16x8*)&Pl[l15][quad * 8];
        bf16x8 ap1 = *(const bf16x8*)&Pl[l15][32 + quad * 8];
#pragma unroll
        for (int dt = 0; dt < 4; ++dt) {
            O[dt] = MFMA16(ap0, vb0[dt], O[dt]);
            O[dt] = MFMA16(ap1, vb1[dt], O[dt]);
        }
    }

    // final l reduction across the 16 lanes of each row group
#pragma unroll
    for (int mask = 1; mask <= 8; mask <<= 1)
#pragma unroll
        for (int r = 0; r < 4; ++r)
            lsum[r] += __shfl_xor(lsum[r], mask, 16);

    float inv[4];
#pragma unroll
    for (int r = 0; r < 4; ++r) inv[r] = 1.f / lsum[r];

#pragma unroll
    for (int dt = 0; dt < 4; ++dt)
#pragma unroll
        for (int r = 0; r < 4; ++r) {
            int nn = n0 + wave * 16 + quad * 4 + r;
            ctx[((size_t)b * SS + nn) * (SH * SD) + h * SD + dt * 16 + l15] =
                f2b(O[dt][r] * inv[r]);
        }
}

// ---------------------------------------------------------------------------
// Kernel 3: output projection, bf16 MFMA GEMM.
// ---------------------------------------------------------------------------
__global__ __launch_bounds__(256) void outproj_kernel(
    const ushort* __restrict__ ctx, const ushort* __restrict__ wt,
    float* __restrict__ out)
{
    __shared__ ushort Asm[128 * 32];
    __shared__ ushort Bsm[128 * 32];

    const int tid  = threadIdx.x;
    const int wave = tid >> 6, lane = tid & 63;
    const int quad = lane >> 4, l15 = lane & 15;
    const int row0 = blockIdx.x * 128;
    const int col0 = blockIdx.y * 128;
    const int wr = wave >> 1, wc = wave & 1;

    const ushort* A  = ctx + (size_t)row0 * SDM;
    const ushort* Bw = wt + (size_t)4 * (SDM * SDM) + (size_t)col0 * SDM;

    f32x4 acc[4][4];
#pragma unroll
    for (int i = 0; i < 4; ++i)
#pragma unroll
        for (int j = 0; j < 4; ++j) acc[i][j] = (f32x4){0.f, 0.f, 0.f, 0.f};

    for (int k0 = 0; k0 < SDM; k0 += 32) {
#pragma unroll
        for (int j = 0; j < 2; ++j) {
            int t = j * 256 + tid;
            int r = t >> 2, kp = (t & 3) * 8;
            gll16(A  + (size_t)r * SDM + k0 + kp, (char*)Asm + t * 16);
            gll16(Bw + (size_t)r * SDM + k0 + kp, (char*)Bsm + t * 16);
        }
        __syncthreads();

        bf16x8 af[4], bfr[4];
#pragma unroll
        for (int mt = 0; mt < 4; ++mt)
            af[mt] = *(const bf16x8*)&Asm[(wr * 64 + mt * 16 + l15) * 32 + quad * 8];
#pragma unroll
        for (int nt = 0; nt < 4; ++nt)
            bfr[nt] = *(const bf16x8*)&Bsm[(wc * 64 + nt * 16 + l15) * 32 + quad * 8];
#pragma unroll
        for (int mt = 0; mt < 4; ++mt)
#pragma unroll
            for (int nt = 0; nt < 4; ++nt)
                acc[mt][nt] = MFMA16(af[mt], bfr[nt], acc[mt][nt]);
        __syncthreads();
    }

#pragma unroll
    for (int mt = 0; mt < 4; ++mt)
#pragma unroll
        for (int nt = 0; nt < 4; ++nt) {
            const int R = row0 + wr * 64 + mt * 16 + quad * 4;
            const int C = col0 + wc * 64 + nt * 16 + l15;
#pragma unroll
            for (int r = 0; r < 4; ++r)
                out[(size_t)(R + r) * SDM + C] = acc[mt][nt][r];
        }
}

// ---------------------------------------------------------------------------
extern "C" void kernel_launch(void* const* d_in, const int* in_sizes, int n_in,
                              void* d_out, int out_size, void* d_ws, size_t ws_size,
                              hipStream_t stream)
{
    const float* query  = (const float*)d_in[0];
    const float* key    = (const float*)d_in[1];
    const float* value  = (const float*)d_in[2];
    const float* pos    = (const float*)d_in[3];
    const float* qw     = (const float*)d_in[4];
    const float* kw     = (const float*)d_in[5];
    const float* vw     = (const float*)d_in[6];
    const float* pw     = (const float*)d_in[7];
    const float* projw  = (const float*)d_in[8];
    const float* bias_u = (const float*)d_in[9];
    const float* bias_v = (const float*)d_in[10];

    char* w = (char*)d_ws;
    const size_t MB = 1024 * 1024;
    ushort* xbf = (ushort*)w;                 // 32 MB (dead after projmm)
    ushort* quo = (ushort*)(w + 32 * MB);
    ushort* qvo = (ushort*)(w + 40 * MB);
    ushort* ko  = (ushort*)(w + 48 * MB);
    ushort* po  = (ushort*)(w + 56 * MB);
    ushort* vto = (ushort*)(w + 64 * MB);     // chunk-tiled [bh][mc][d][64]
    ushort* wt  = (ushort*)(w + 72 * MB);     // 2.5 MB
    ushort* ctx = (ushort*)w;                 // aliases dead xbf

    dim3 gcx(2048, 4);
    convert_x_kernel<<<gcx, 256, 0, stream>>>(query, key, value, pos, xbf);
    dim3 gcw(1024, 5);
    convert_w_kernel<<<gcw, 256, 0, stream>>>(qw, kw, vw, pw, projw, wt);

    dim3 g1(64, 4, 4);
    projmm_kernel<<<g1, 256, 0, stream>>>(xbf, wt, bias_u, bias_v,
                                          quo, qvo, ko, po, vto);

    attn_kernel<<<dim3(1024), 256, 0, stream>>>(quo, qvo, ko, po, vto, ctx);

    dim3 g3(64, 4);
    outproj_kernel<<<g3, 256, 0, stream>>>(ctx, wt, (float*)d_out);
}

// Round 7
// 315.151 us; speedup vs baseline: 1.3437x; 1.1953x over previous
//
#include <hip/hip_runtime.h>
#include <hip/hip_bf16.h>
#include <math.h>

#define SB 8     // batch
#define SS 1024  // N == M
#define SDM 512  // model dim
#define SH 8     // heads
#define SD 64    // head dim

typedef unsigned short ushort;
typedef __attribute__((ext_vector_type(8))) short bf16x8;
typedef __attribute__((ext_vector_type(4))) float f32x4;

#define MFMA16(a, b, c) __builtin_amdgcn_mfma_f32_16x16x32_bf16(a, b, c, 0, 0, 0)

static __device__ __forceinline__ ushort f2b(float f) {
    union { float f; unsigned u; } v; v.f = f;
    unsigned r = v.u + 0x7FFF + ((v.u >> 16) & 1);   // round-nearest-even
    return (ushort)(r >> 16);
}

// async global->LDS, 16 bytes per lane (dest = wave-uniform base + lane*16)
static __device__ __forceinline__ void gll16(const void* g, void* l) {
    __builtin_amdgcn_global_load_lds(
        (const __attribute__((address_space(1))) unsigned int*)g,
        (__attribute__((address_space(3))) unsigned int*)l, 16, 0, 0);
}

// ---------------------------------------------------------------------------
// Convert inputs X (q,k,v,pos) fp32 -> bf16, 8 elems/thread. grid (2048, 4).
// ---------------------------------------------------------------------------
__global__ __launch_bounds__(256) void convert_x_kernel(
    const float* __restrict__ q, const float* __restrict__ k,
    const float* __restrict__ v, const float* __restrict__ p,
    ushort* __restrict__ xbf)
{
    const int which = blockIdx.y;
    const float* src = (which == 0) ? q : (which == 1) ? k : (which == 2) ? v : p;
    ushort* dst = xbf + (size_t)which * ((size_t)SB * SS * SDM);
    size_t i = ((size_t)blockIdx.x * 256 + threadIdx.x) * 8;
    float4 a = *(const float4*)(src + i);
    float4 b = *(const float4*)(src + i + 4);
    union { ushort u[8]; uint4 v4; } o;
    o.u[0] = f2b(a.x); o.u[1] = f2b(a.y); o.u[2] = f2b(a.z); o.u[3] = f2b(a.w);
    o.u[4] = f2b(b.x); o.u[5] = f2b(b.y); o.u[6] = f2b(b.z); o.u[7] = f2b(b.w);
    *(uint4*)(dst + i) = o.v4;
}

// ---------------------------------------------------------------------------
// Convert weights -> transposed bf16 Wt[which][col][k].
// ---------------------------------------------------------------------------
__global__ __launch_bounds__(256) void convert_w_kernel(
    const float* __restrict__ qw, const float* __restrict__ kw,
    const float* __restrict__ vw, const float* __restrict__ pw,
    const float* __restrict__ projw, ushort* __restrict__ wt)
{
    const int which = blockIdx.y;
    const int idx = blockIdx.x * 256 + threadIdx.x;
    const int c  = idx >> 9;
    const int kk = idx & 511;
    float val;
    if (which < 4) {
        const float* W = (which == 0) ? qw : (which == 1) ? kw : (which == 2) ? vw : pw;
        const int h = c >> 6, d = c & 63;
        val = W[(size_t)h * SDM * SD + (size_t)kk * SD + d];
    } else {
        val = projw[(size_t)kk * SDM + c];
    }
    wt[(size_t)which * SDM * SDM + (size_t)c * SDM + kk] = f2b(val);
}

// ---------------------------------------------------------------------------
// Kernel 1: bf16 MFMA projection GEMM, 128x128 tile.
// q_u / q_v pre-scaled by 1/sqrt(D). v written chunk-tiled: [bh][mc][d][64].
// ---------------------------------------------------------------------------
__global__ __launch_bounds__(256) void projmm_kernel(
    const ushort* __restrict__ xbf, const ushort* __restrict__ wt,
    const float* __restrict__ bias_u, const float* __restrict__ bias_v,
    ushort* __restrict__ quo, ushort* __restrict__ qvo,
    ushort* __restrict__ ko, ushort* __restrict__ po,
    ushort* __restrict__ vto)
{
    __shared__ ushort Asm[128 * 32];
    __shared__ ushort Bsm[128 * 32];

    const int tid  = threadIdx.x;
    const int wave = tid >> 6, lane = tid & 63;
    const int quad = lane >> 4, l15 = lane & 15;
    const int which = blockIdx.z;
    const int row0 = blockIdx.x * 128;
    const int col0 = blockIdx.y * 128;
    const int wr = wave >> 1, wc = wave & 1;

    const ushort* A  = xbf + (size_t)which * ((size_t)SB * SS * SDM) + (size_t)row0 * SDM;
    const ushort* Bw = wt  + (size_t)which * (SDM * SDM) + (size_t)col0 * SDM;

    f32x4 acc[4][4];
#pragma unroll
    for (int i = 0; i < 4; ++i)
#pragma unroll
        for (int j = 0; j < 4; ++j) acc[i][j] = (f32x4){0.f, 0.f, 0.f, 0.f};

    for (int k0 = 0; k0 < SDM; k0 += 32) {
#pragma unroll
        for (int j = 0; j < 2; ++j) {
            int t = j * 256 + tid;
            int r = t >> 2, kp = (t & 3) * 8;
            gll16(A  + (size_t)r * SDM + k0 + kp, (char*)Asm + t * 16);
            gll16(Bw + (size_t)r * SDM + k0 + kp, (char*)Bsm + t * 16);
        }
        __syncthreads();

        bf16x8 af[4], bfr[4];
#pragma unroll
        for (int mt = 0; mt < 4; ++mt)
            af[mt] = *(const bf16x8*)&Asm[(wr * 64 + mt * 16 + l15) * 32 + quad * 8];
#pragma unroll
        for (int nt = 0; nt < 4; ++nt)
            bfr[nt] = *(const bf16x8*)&Bsm[(wc * 64 + nt * 16 + l15) * 32 + quad * 8];
#pragma unroll
        for (int mt = 0; mt < 4; ++mt)
#pragma unroll
            for (int nt = 0; nt < 4; ++nt)
                acc[mt][nt] = MFMA16(af[mt], bfr[nt], acc[mt][nt]);
        __syncthreads();
    }

    const float SC = 0.125f;   // 1/sqrt(D) folded into q
#pragma unroll
    for (int nt = 0; nt < 4; ++nt) {
        const int C = col0 + wc * 64 + nt * 16 + l15;
        const int h = C >> 6, d = C & 63;
        if (which == 0) {
            const float bu = bias_u[C];
            const float bv = bias_v[C];
#pragma unroll
            for (int mt = 0; mt < 4; ++mt) {
                const int Rb = row0 + wr * 64 + mt * 16 + quad * 4;
                const int b = Rb >> 10;
                const int n = Rb & 1023;
                const size_t base = ((size_t)(b * SH + h) * SS + n) * SD + d;
#pragma unroll
                for (int r = 0; r < 4; ++r) {
                    quo[base + (size_t)r * SD] = f2b((acc[mt][nt][r] + bu) * SC);
                    qvo[base + (size_t)r * SD] = f2b((acc[mt][nt][r] + bv) * SC);
                }
            }
        } else if (which == 1 || which == 3) {
            ushort* out = (which == 1) ? ko : po;
#pragma unroll
            for (int mt = 0; mt < 4; ++mt) {
                const int Rb = row0 + wr * 64 + mt * 16 + quad * 4;
                const int b = Rb >> 10;
                const int n = Rb & 1023;
                const size_t base = ((size_t)(b * SH + h) * SS + n) * SD + d;
#pragma unroll
                for (int r = 0; r < 4; ++r)
                    out[base + (size_t)r * SD] = f2b(acc[mt][nt][r]);
            }
        } else {
            // v chunk-tiled: vto[bh][n>>6][d][64]
#pragma unroll
            for (int mt = 0; mt < 4; ++mt) {
                const int Rb = row0 + wr * 64 + mt * 16 + quad * 4;
                const int b = Rb >> 10;
                const int n = Rb & 1023;
                union { ushort u[4]; uint2 v2; } pk;
#pragma unroll
                for (int r = 0; r < 4; ++r) pk.u[r] = f2b(acc[mt][nt][r]);
                const size_t base = (size_t)(b * SH + h) * SS * SD
                                  + ((size_t)((n >> 6) * 64 + d)) * 64 + (n & 63);
                *(uint2*)&vto[base] = pk.v2;
            }
        }
    }
}

// XOR-swizzled LDS fragment read: 16B segment `seg` of logical row `row`
// (row stride 64 ushorts = 128 B; store placed seg at slot seg^(row&7)).
static __device__ __forceinline__ bf16x8 sfrag(const ushort* buf, int row, int seg) {
    return *(const bf16x8*)&buf[(size_t)row * 64 + ((seg ^ (row & 7)) * 8)];
}

// ---------------------------------------------------------------------------
// Kernel 2: bf16 MFMA attention. Staged skeleton (Kb/Pb via global_load_lds
// + barriers; stage(mc+1) before exp/PV) + parallel in-register diagonal
// gather (20 independent __shfl + selects). REGISTER-PRESSURE tuned: round-6
// measured VGPR=132, just over the 128 HW boundary -> waves/SIMD 4->2,
// occupancy 11%. Fixes to get <=128 (no launch-bounds forcing - that
// spilled at 64 in round 1):
//  (a) band GEMM under a BLOCK-UNIFORM if/else on lowerband instead of
//      `av = cond ? a_vl : a_vu` (the ?: kept 8 extra cndmask copies live);
//  (b) gsrc/ghi recomputed locally per gather block (was 8 hoisted regs);
//  (c) v-burst issued AFTER the gather (was before: 16 regs live across
//      the whole shuffle phase); exp+Plds round-trip still covers its L2
//      latency before first PV use.
// LDS ~33.8 KB -> 4 blocks/CU; grid 1024 = exactly 4x256 CUs, tail-free.
// XCD-clustered grid: all 16 n-tiles of a (b,h) share an XCD L2.
// ---------------------------------------------------------------------------
__global__ __launch_bounds__(256) void attn_kernel(
    const ushort* __restrict__ qu, const ushort* __restrict__ qv,
    const ushort* __restrict__ kk, const ushort* __restrict__ pp,
    const ushort* __restrict__ vt, ushort* __restrict__ ctx)
{
    __shared__ ushort Kb[64 * 64];       //  8 KB staged k chunk
    __shared__ ushort Pb[128 * 64];      // 16 KB staged p band
    __shared__ ushort Plds[4][16][72];   //  9 KB P C->A transform (wave-private)

    const int tid  = threadIdx.x;
    const int wave = tid >> 6;
    const int lane = tid & 63;
    const int quad = lane >> 4;
    const int l15  = lane & 15;

    const int id   = blockIdx.x;
    const int xcd  = id & 7;
    const int slot = id >> 3;               // 0..127
    const int bhid = xcd * 8 + (slot >> 4); // 0..63
    const int nt   = slot & 15;
    const int b    = bhid >> 3;
    const int h    = bhid & 7;
    const int n0   = nt * 64;

    const size_t bh   = (size_t)(b * SH + h);
    const ushort* qu_bh = qu + bh * SS * SD;
    const ushort* qv_bh = qv + bh * SS * SD;
    const ushort* k_bh  = kk + bh * SS * SD;
    const ushort* p_bh  = pp + bh * SS * SD;
    const ushort* vt_bh = vt + bh * SS * SD;   // chunk-tiled [mc][d][64]

    const int mcD = n0 >> 6;   // diagonal chunk index

    const int arow  = n0 + wave * 16 + l15;
    const int arow2 = (arow + 1 < SS) ? arow + 1 : SS - 1;

    bf16x8 a_u0  = *(const bf16x8*)(qu_bh + (size_t)arow  * SD + quad * 8);
    bf16x8 a_u1  = *(const bf16x8*)(qu_bh + (size_t)arow  * SD + quad * 8 + 32);
    bf16x8 a_vl0 = *(const bf16x8*)(qv_bh + (size_t)arow  * SD + quad * 8);
    bf16x8 a_vl1 = *(const bf16x8*)(qv_bh + (size_t)arow  * SD + quad * 8 + 32);
    bf16x8 a_vu0 = *(const bf16x8*)(qv_bh + (size_t)arow2 * SD + quad * 8);
    bf16x8 a_vu1 = *(const bf16x8*)(qv_bh + (size_t)arow2 * SD + quad * 8 + 32);

    float lsum[4] = {0.f, 0.f, 0.f, 0.f};
    f32x4 O[4];
#pragma unroll
    for (int dt = 0; dt < 4; ++dt) O[dt] = (f32x4){0.f, 0.f, 0.f, 0.f};

    ushort (*Pl)[72] = Plds[wave];

    // stage chunk mc's k (64 rows) + p band (128 rows) into LDS, XOR-swizzled
    auto stage = [&](int mc) {
        const int m0s = mc * 64;
        const int cb  = (mc <= mcD) ? (m0s - n0 + 960) : (m0s - n0 - 65);
#pragma unroll
        for (int it = 0; it < 2; ++it) {
            int t = it * 256 + tid;
            int r = t >> 3, s = t & 7;
            gll16(k_bh + (size_t)(m0s + r) * 64 + ((s ^ (r & 7)) * 8),
                  (char*)Kb + t * 16);
        }
#pragma unroll
        for (int it = 0; it < 4; ++it) {
            int t = it * 256 + tid;
            int r = t >> 3, s = t & 7;
            int c = cb + r; c = (c < 0) ? 0 : (c > SS - 1 ? SS - 1 : c);
            gll16(p_bh + (size_t)c * 64 + ((s ^ (r & 7)) * 8),
                  (char*)Pb + t * 16);
        }
    };

    stage(0);

    for (int mc = 0; mc < 16; ++mc) {
        const int m0 = mc * 64;
        const int diff = m0 - n0;
        const bool lowerband = (mc <= mcD);

        __syncthreads();   // staged data ready (compiler drains vmcnt before barrier)

        // ---- S_u = q_u . k^T from staged Kb ----
        f32x4 S[4];
#pragma unroll
        for (int mt = 0; mt < 4; ++mt) {
            const int r = mt * 16 + l15;
            f32x4 c = (f32x4){0.f, 0.f, 0.f, 0.f};
            c = MFMA16(a_u0, sfrag(Kb, r, quad), c);
            c = MFMA16(a_u1, sfrag(Kb, r, quad + 4), c);
            S[mt] = c;
        }

        // ---- band GEMM from staged Pb (block-uniform branch: no cndmask
        //      copies of the q_v fragments) ----
        f32x4 g[5];
        if (lowerband) {
#pragma unroll
            for (int ti = 0; ti < 5; ++ti) {
                const int t = (3 - wave + ti) * 16 + l15;
                f32x4 gg = (f32x4){0.f, 0.f, 0.f, 0.f};
                gg = MFMA16(a_vl0, sfrag(Pb, t, quad), gg);
                gg = MFMA16(a_vl1, sfrag(Pb, t, quad + 4), gg);
                g[ti] = gg;
            }
        } else {
#pragma unroll
            for (int ti = 0; ti < 5; ++ti) {
                const int t = (3 - wave + ti) * 16 + l15;
                f32x4 gg = (f32x4){0.f, 0.f, 0.f, 0.f};
                gg = MFMA16(a_vu0, sfrag(Pb, t, quad), gg);
                gg = MFMA16(a_vu1, sfrag(Pb, t, quad + 4), gg);
                g[ti] = gg;
            }
        }

        // ---- parallel in-register diagonal gather (20 independent shfl);
        //      gsrc/ghi recomputed locally (rematerialized, not hoisted) ----
        float sv[4][4];
        {
            const int dbase = diff + l15 - wave * 16 - quad * 4; // d1 = dbase+16mt-r
#pragma unroll
            for (int r = 0; r < 4; ++r) {
                const int o   = l15 + 15 - quad * 4 - r;
                const int src = (lane & 48) | (o & 15);
                const bool hi = (o >= 16);
                float hh[5];
#pragma unroll
                for (int ti = 0; ti < 5; ++ti)
                    hh[ti] = __shfl(g[ti][r], src);
                const int d1b = dbase - r;
#pragma unroll
                for (int mt = 0; mt < 4; ++mt) {
                    const float v = hi ? hh[mt + 1] : hh[mt];
                    const int d1 = d1b + 16 * mt;
                    const bool use = lowerband ? (d1 <= 0) : (d1 >= 2);
                    sv[mt][r] = use ? v : 0.f;
                }
            }
        }

        // ---- diagonal chunk: upper band direct from global, same gather ----
        if (mc == mcD) {
            const int cbase = diff - 65;
            f32x4 gd[5];
#pragma unroll
            for (int ti = 0; ti < 5; ++ti) {
                int c = cbase + (3 - wave + ti) * 16 + l15;
                c = (c < 0) ? 0 : (c > SS - 1 ? SS - 1 : c);
                const ushort* pr = p_bh + (size_t)c * SD + quad * 8;
                f32x4 gg = (f32x4){0.f, 0.f, 0.f, 0.f};
                gg = MFMA16(a_vu0, *(const bf16x8*)pr, gg);
                gg = MFMA16(a_vu1, *(const bf16x8*)(pr + 32), gg);
                gd[ti] = gg;
            }
            const int dbase = diff + l15 - wave * 16 - quad * 4;
#pragma unroll
            for (int r = 0; r < 4; ++r) {
                const int o   = l15 + 15 - quad * 4 - r;
                const int src = (lane & 48) | (o & 15);
                const bool hi = (o >= 16);
                float hh[5];
#pragma unroll
                for (int ti = 0; ti < 5; ++ti)
                    hh[ti] = __shfl(gd[ti][r], src);
                const int d1b = dbase - r;
#pragma unroll
                for (int mt = 0; mt < 4; ++mt) {
                    const float v = hi ? hh[mt + 1] : hh[mt];
                    if (d1b + 16 * mt >= 2) sv[mt][r] = v;
                }
            }
        }

        __syncthreads();   // all waves done reading Kb/Pb
        if (mc + 1 < 16) stage(mc + 1);   // DMA overlaps exp/PV below

        // ---- v burst (after gather: 16 regs not live across shuffles;
        //      exp + Plds round-trip below covers the L2 latency) ----
        bf16x8 vb0[4], vb1[4];
#pragma unroll
        for (int dt = 0; dt < 4; ++dt) {
            const ushort* vp = vt_bh + (size_t)(m0 + dt * 16 + l15) * 64 + quad * 8;
            vb0[dt] = *(const bf16x8*)vp;
            vb1[dt] = *(const bf16x8*)(vp + 32);
        }

        // ---- e = exp(logit), lane-local l accumulation ----
        float e[4][4];
#pragma unroll
        for (int mt = 0; mt < 4; ++mt)
#pragma unroll
            for (int r = 0; r < 4; ++r) {
                e[mt][r] = __expf(S[mt][r] + sv[mt][r]);
                lsum[r] += e[mt][r];
            }

        // ---- P: C-layout -> A-layout via wave-private LDS ----
#pragma unroll
        for (int mt = 0; mt < 4; ++mt)
#pragma unroll
            for (int r = 0; r < 4; ++r)
                Pl[quad * 4 + r][mt * 16 + l15] = f2b(e[mt][r]);

        // ---- O += P . V ----
        bf16x8 ap0 = *(const bf16x8*)&Pl[l15][quad * 8];
        bf16x8 ap1 = *(const bf16x8*)&Pl[l15][32 + quad * 8];
#pragma unroll
        for (int dt = 0; dt < 4; ++dt) {
            O[dt] = MFMA16(ap0, vb0[dt], O[dt]);
            O[dt] = MFMA16(ap1, vb1[dt], O[dt]);
        }
    }

    // final l reduction across the 16 lanes of each row group
#pragma unroll
    for (int mask = 1; mask <= 8; mask <<= 1)
#pragma unroll
        for (int r = 0; r < 4; ++r)
            lsum[r] += __shfl_xor(lsum[r], mask, 16);

    float inv[4];
#pragma unroll
    for (int r = 0; r < 4; ++r) inv[r] = 1.f / lsum[r];

#pragma unroll
    for (int dt = 0; dt < 4; ++dt)
#pragma unroll
        for (int r = 0; r < 4; ++r) {
            int nn = n0 + wave * 16 + quad * 4 + r;
            ctx[((size_t)b * SS + nn) * (SH * SD) + h * SD + dt * 16 + l15] =
                f2b(O[dt][r] * inv[r]);
        }
}

// ---------------------------------------------------------------------------
// Kernel 3: output projection, bf16 MFMA GEMM.
// ---------------------------------------------------------------------------
__global__ __launch_bounds__(256) void outproj_kernel(
    const ushort* __restrict__ ctx, const ushort* __restrict__ wt,
    float* __restrict__ out)
{
    __shared__ ushort Asm[128 * 32];
    __shared__ ushort Bsm[128 * 32];

    const int tid  = threadIdx.x;
    const int wave = tid >> 6, lane = tid & 63;
    const int quad = lane >> 4, l15 = lane & 15;
    const int row0 = blockIdx.x * 128;
    const int col0 = blockIdx.y * 128;
    const int wr = wave >> 1, wc = wave & 1;

    const ushort* A  = ctx + (size_t)row0 * SDM;
    const ushort* Bw = wt + (size_t)4 * (SDM * SDM) + (size_t)col0 * SDM;

    f32x4 acc[4][4];
#pragma unroll
    for (int i = 0; i < 4; ++i)
#pragma unroll
        for (int j = 0; j < 4; ++j) acc[i][j] = (f32x4){0.f, 0.f, 0.f, 0.f};

    for (int k0 = 0; k0 < SDM; k0 += 32) {
#pragma unroll
        for (int j = 0; j < 2; ++j) {
            int t = j * 256 + tid;
            int r = t >> 2, kp = (t & 3) * 8;
            gll16(A  + (size_t)r * SDM + k0 + kp, (char*)Asm + t * 16);
            gll16(Bw + (size_t)r * SDM + k0 + kp, (char*)Bsm + t * 16);
        }
        __syncthreads();

        bf16x8 af[4], bfr[4];
#pragma unroll
        for (int mt = 0; mt < 4; ++mt)
            af[mt] = *(const bf16x8*)&Asm[(wr * 64 + mt * 16 + l15) * 32 + quad * 8];
#pragma unroll
        for (int nt = 0; nt < 4; ++nt)
            bfr[nt] = *(const bf16x8*)&Bsm[(wc * 64 + nt * 16 + l15) * 32 + quad * 8];
#pragma unroll
        for (int mt = 0; mt < 4; ++mt)
#pragma unroll
            for (int nt = 0; nt < 4; ++nt)
                acc[mt][nt] = MFMA16(af[mt], bfr[nt], acc[mt][nt]);
        __syncthreads();
    }

#pragma unroll
    for (int mt = 0; mt < 4; ++mt)
#pragma unroll
        for (int nt = 0; nt < 4; ++nt) {
            const int R = row0 + wr * 64 + mt * 16 + quad * 4;
            const int C = col0 + wc * 64 + nt * 16 + l15;
#pragma unroll
            for (int r = 0; r < 4; ++r)
                out[(size_t)(R + r) * SDM + C] = acc[mt][nt][r];
        }
}

// ---------------------------------------------------------------------------
extern "C" void kernel_launch(void* const* d_in, const int* in_sizes, int n_in,
                              void* d_out, int out_size, void* d_ws, size_t ws_size,
                              hipStream_t stream)
{
    const float* query  = (const float*)d_in[0];
    const float* key    = (const float*)d_in[1];
    const float* value  = (const float*)d_in[2];
    const float* pos    = (const float*)d_in[3];
    const float* qw     = (const float*)d_in[4];
    const float* kw     = (const float*)d_in[5];
    const float* vw     = (const float*)d_in[6];
    const float* pw     = (const float*)d_in[7];
    const float* projw  = (const float*)d_in[8];
    const float* bias_u = (const float*)d_in[9];
    const float* bias_v = (const float*)d_in[10];

    char* w = (char*)d_ws;
    const size_t MB = 1024 * 1024;
    ushort* xbf = (ushort*)w;                 // 32 MB (dead after projmm)
    ushort* quo = (ushort*)(w + 32 * MB);
    ushort* qvo = (ushort*)(w + 40 * MB);
    ushort* ko  = (ushort*)(w + 48 * MB);
    ushort* po  = (ushort*)(w + 56 * MB);
    ushort* vto = (ushort*)(w + 64 * MB);     // chunk-tiled [bh][mc][d][64]
    ushort* wt  = (ushort*)(w + 72 * MB);     // 2.5 MB
    ushort* ctx = (ushort*)w;                 // aliases dead xbf

    dim3 gcx(2048, 4);
    convert_x_kernel<<<gcx, 256, 0, stream>>>(query, key, value, pos, xbf);
    dim3 gcw(1024, 5);
    convert_w_kernel<<<gcw, 256, 0, stream>>>(qw, kw, vw, pw, projw, wt);

    dim3 g1(64, 4, 4);
    projmm_kernel<<<g1, 256, 0, stream>>>(xbf, wt, bias_u, bias_v,
                                          quo, qvo, ko, po, vto);

    attn_kernel<<<dim3(1024), 256, 0, stream>>>(quo, qvo, ko, po, vto, ctx);

    dim3 g3(64, 4);
    outproj_kernel<<<g3, 256, 0, stream>>>(ctx, wt, (float*)d_out);
}

// Round 8
// 273.337 us; speedup vs baseline: 1.5493x; 1.1530x over previous
//
#include <hip/hip_runtime.h>
#include <hip/hip_bf16.h>
#include <math.h>

#define SB 8     // batch
#define SS 1024  // N == M
#define SDM 512  // model dim
#define SH 8     // heads
#define SD 64    // head dim

typedef unsigned short ushort;
typedef __attribute__((ext_vector_type(8))) short bf16x8;
typedef __attribute__((ext_vector_type(4))) float f32x4;

#define MFMA16(a, b, c) __builtin_amdgcn_mfma_f32_16x16x32_bf16(a, b, c, 0, 0, 0)

static __device__ __forceinline__ ushort f2b(float f) {
    union { float f; unsigned u; } v; v.f = f;
    unsigned r = v.u + 0x7FFF + ((v.u >> 16) & 1);   // round-nearest-even
    return (ushort)(r >> 16);
}

// async global->LDS, 16 bytes per lane (dest = wave-uniform base + lane*16)
static __device__ __forceinline__ void gll16(const void* g, void* l) {
    __builtin_amdgcn_global_load_lds(
        (const __attribute__((address_space(1))) unsigned int*)g,
        (__attribute__((address_space(3))) unsigned int*)l, 16, 0, 0);
}

// ---------------------------------------------------------------------------
// Convert inputs X (q,k,v,pos) fp32 -> bf16, 8 elems/thread. grid (2048, 4).
// ---------------------------------------------------------------------------
__global__ __launch_bounds__(256) void convert_x_kernel(
    const float* __restrict__ q, const float* __restrict__ k,
    const float* __restrict__ v, const float* __restrict__ p,
    ushort* __restrict__ xbf)
{
    const int which = blockIdx.y;
    const float* src = (which == 0) ? q : (which == 1) ? k : (which == 2) ? v : p;
    ushort* dst = xbf + (size_t)which * ((size_t)SB * SS * SDM);
    size_t i = ((size_t)blockIdx.x * 256 + threadIdx.x) * 8;
    float4 a = *(const float4*)(src + i);
    float4 b = *(const float4*)(src + i + 4);
    union { ushort u[8]; uint4 v4; } o;
    o.u[0] = f2b(a.x); o.u[1] = f2b(a.y); o.u[2] = f2b(a.z); o.u[3] = f2b(a.w);
    o.u[4] = f2b(b.x); o.u[5] = f2b(b.y); o.u[6] = f2b(b.z); o.u[7] = f2b(b.w);
    *(uint4*)(dst + i) = o.v4;
}

// ---------------------------------------------------------------------------
// Convert weights -> transposed bf16 Wt[which][col][k].
// ---------------------------------------------------------------------------
__global__ __launch_bounds__(256) void convert_w_kernel(
    const float* __restrict__ qw, const float* __restrict__ kw,
    const float* __restrict__ vw, const float* __restrict__ pw,
    const float* __restrict__ projw, ushort* __restrict__ wt)
{
    const int which = blockIdx.y;
    const int idx = blockIdx.x * 256 + threadIdx.x;
    const int c  = idx >> 9;
    const int kk = idx & 511;
    float val;
    if (which < 4) {
        const float* W = (which == 0) ? qw : (which == 1) ? kw : (which == 2) ? vw : pw;
        const int h = c >> 6, d = c & 63;
        val = W[(size_t)h * SDM * SD + (size_t)kk * SD + d];
    } else {
        val = projw[(size_t)kk * SDM + c];
    }
    wt[(size_t)which * SDM * SDM + (size_t)c * SDM + kk] = f2b(val);
}

// ---------------------------------------------------------------------------
// Kernel 1: bf16 MFMA projection GEMM, 128x128 tile.
// q_u / q_v pre-scaled by 1/sqrt(D). v written chunk-tiled: [bh][mc][d][64].
// ---------------------------------------------------------------------------
__global__ __launch_bounds__(256) void projmm_kernel(
    const ushort* __restrict__ xbf, const ushort* __restrict__ wt,
    const float* __restrict__ bias_u, const float* __restrict__ bias_v,
    ushort* __restrict__ quo, ushort* __restrict__ qvo,
    ushort* __restrict__ ko, ushort* __restrict__ po,
    ushort* __restrict__ vto)
{
    __shared__ ushort Asm[128 * 32];
    __shared__ ushort Bsm[128 * 32];

    const int tid  = threadIdx.x;
    const int wave = tid >> 6, lane = tid & 63;
    const int quad = lane >> 4, l15 = lane & 15;
    const int which = blockIdx.z;
    const int row0 = blockIdx.x * 128;
    const int col0 = blockIdx.y * 128;
    const int wr = wave >> 1, wc = wave & 1;

    const ushort* A  = xbf + (size_t)which * ((size_t)SB * SS * SDM) + (size_t)row0 * SDM;
    const ushort* Bw = wt  + (size_t)which * (SDM * SDM) + (size_t)col0 * SDM;

    f32x4 acc[4][4];
#pragma unroll
    for (int i = 0; i < 4; ++i)
#pragma unroll
        for (int j = 0; j < 4; ++j) acc[i][j] = (f32x4){0.f, 0.f, 0.f, 0.f};

    for (int k0 = 0; k0 < SDM; k0 += 32) {
#pragma unroll
        for (int j = 0; j < 2; ++j) {
            int t = j * 256 + tid;
            int r = t >> 2, kp = (t & 3) * 8;
            gll16(A  + (size_t)r * SDM + k0 + kp, (char*)Asm + t * 16);
            gll16(Bw + (size_t)r * SDM + k0 + kp, (char*)Bsm + t * 16);
        }
        __syncthreads();

        bf16x8 af[4], bfr[4];
#pragma unroll
        for (int mt = 0; mt < 4; ++mt)
            af[mt] = *(const bf16x8*)&Asm[(wr * 64 + mt * 16 + l15) * 32 + quad * 8];
#pragma unroll
        for (int nt = 0; nt < 4; ++nt)
            bfr[nt] = *(const bf16x8*)&Bsm[(wc * 64 + nt * 16 + l15) * 32 + quad * 8];
#pragma unroll
        for (int mt = 0; mt < 4; ++mt)
#pragma unroll
            for (int nt = 0; nt < 4; ++nt)
                acc[mt][nt] = MFMA16(af[mt], bfr[nt], acc[mt][nt]);
        __syncthreads();
    }

    const float SC = 0.125f;   // 1/sqrt(D) folded into q
#pragma unroll
    for (int nt = 0; nt < 4; ++nt) {
        const int C = col0 + wc * 64 + nt * 16 + l15;
        const int h = C >> 6, d = C & 63;
        if (which == 0) {
            const float bu = bias_u[C];
            const float bv = bias_v[C];
#pragma unroll
            for (int mt = 0; mt < 4; ++mt) {
                const int Rb = row0 + wr * 64 + mt * 16 + quad * 4;
                const int b = Rb >> 10;
                const int n = Rb & 1023;
                const size_t base = ((size_t)(b * SH + h) * SS + n) * SD + d;
#pragma unroll
                for (int r = 0; r < 4; ++r) {
                    quo[base + (size_t)r * SD] = f2b((acc[mt][nt][r] + bu) * SC);
                    qvo[base + (size_t)r * SD] = f2b((acc[mt][nt][r] + bv) * SC);
                }
            }
        } else if (which == 1 || which == 3) {
            ushort* out = (which == 1) ? ko : po;
#pragma unroll
            for (int mt = 0; mt < 4; ++mt) {
                const int Rb = row0 + wr * 64 + mt * 16 + quad * 4;
                const int b = Rb >> 10;
                const int n = Rb & 1023;
                const size_t base = ((size_t)(b * SH + h) * SS + n) * SD + d;
#pragma unroll
                for (int r = 0; r < 4; ++r)
                    out[base + (size_t)r * SD] = f2b(acc[mt][nt][r]);
            }
        } else {
            // v chunk-tiled: vto[bh][n>>6][d][64]
#pragma unroll
            for (int mt = 0; mt < 4; ++mt) {
                const int Rb = row0 + wr * 64 + mt * 16 + quad * 4;
                const int b = Rb >> 10;
                const int n = Rb & 1023;
                union { ushort u[4]; uint2 v2; } pk;
#pragma unroll
                for (int r = 0; r < 4; ++r) pk.u[r] = f2b(acc[mt][nt][r]);
                const size_t base = (size_t)(b * SH + h) * SS * SD
                                  + ((size_t)((n >> 6) * 64 + d)) * 64 + (n & 63);
                *(uint2*)&vto[base] = pk.v2;
            }
        }
    }
}

// XOR-swizzled LDS fragment read: 16B segment `seg` of logical row `row`
// (row stride 64 ushorts = 128 B; store placed seg at slot seg^(row&7)).
static __device__ __forceinline__ bf16x8 sfrag(const ushort* buf, int row, int seg) {
    return *(const bf16x8*)&buf[(size_t)row * 64 + ((seg ^ (row & 7)) * 8)];
}

// ---------------------------------------------------------------------------
// Kernel 2: bf16 MFMA attention — round-0 skeleton (best measured: 102 us),
// with ONE surgical change: the Glds gather scratch stride 80 -> 83.
// Round-0's [16][80] layout had write bank = (16r + l15) mod 32, quad-
// INDEPENDENT -> uniform 4-way write conflicts (5.43 M cycles). For stride
// s: write spread needs s odd, read spread needs (s-1) == 2 (mod 4); both
// hold iff s == 3 (mod 4). s=83: write banks offset {0,12,24,4} per quad
// (mostly 2-way, free per HW), read banks offset {0,8,16,24} (uniform
// 2-way, free). To keep LDS at 3 blocks/CU despite the wider stride, Glds
// and Plds are UNIONed: they are used in disjoint phases of each chunk
// (gather reads complete before the P-transform writes; same-wave DS ops
// are in-order), and both are wave-private. LDS total 45.8 KB -> 3
// blocks/CU, same residency as round 0.
// Evidence trail: bpermute-gather variants (r2,6,7) all lost to this
// skeleton at iso-occupancy; zero-staging (r3) lost 2.5x; forced
// launch_bounds (r1) spilled. Do not revisit those.
// XCD-clustered grid (1024): all 16 n-tiles of a (b,h) share an XCD L2.
// ---------------------------------------------------------------------------
__global__ __launch_bounds__(256) void attn_kernel(
    const ushort* __restrict__ qu, const ushort* __restrict__ qv,
    const ushort* __restrict__ kk, const ushort* __restrict__ pp,
    const ushort* __restrict__ vt, ushort* __restrict__ ctx)
{
    union GPshare {
        float  g[16][83];   // 5312 B gather scratch (stride 83: see header)
        ushort p[16][72];   // 2304 B P C->A transform
    };
    __shared__ ushort  Kb[64 * 64];      //  8 KB staged k chunk
    __shared__ ushort  Pb[128 * 64];     // 16 KB staged p band
    __shared__ GPshare GP[4];            // 21.25 KB wave-private (union)

    const int tid  = threadIdx.x;
    const int wave = tid >> 6;
    const int lane = tid & 63;
    const int quad = lane >> 4;
    const int l15  = lane & 15;

    const int id   = blockIdx.x;
    const int xcd  = id & 7;
    const int slot = id >> 3;               // 0..127
    const int bhid = xcd * 8 + (slot >> 4); // 0..63
    const int nt   = slot & 15;
    const int b    = bhid >> 3;
    const int h    = bhid & 7;
    const int n0   = nt * 64;

    const size_t bh   = (size_t)(b * SH + h);
    const ushort* qu_bh = qu + bh * SS * SD;
    const ushort* qv_bh = qv + bh * SS * SD;
    const ushort* k_bh  = kk + bh * SS * SD;
    const ushort* p_bh  = pp + bh * SS * SD;
    const ushort* vt_bh = vt + bh * SS * SD;   // chunk-tiled [mc][d][64]

    const int mcD = n0 >> 6;   // diagonal chunk index

    const int arow  = n0 + wave * 16 + l15;
    const int arow2 = (arow + 1 < SS) ? arow + 1 : SS - 1;

    bf16x8 a_u0  = *(const bf16x8*)(qu_bh + (size_t)arow  * SD + quad * 8);
    bf16x8 a_u1  = *(const bf16x8*)(qu_bh + (size_t)arow  * SD + quad * 8 + 32);
    bf16x8 a_vl0 = *(const bf16x8*)(qv_bh + (size_t)arow  * SD + quad * 8);
    bf16x8 a_vl1 = *(const bf16x8*)(qv_bh + (size_t)arow  * SD + quad * 8 + 32);
    bf16x8 a_vu0 = *(const bf16x8*)(qv_bh + (size_t)arow2 * SD + quad * 8);
    bf16x8 a_vu1 = *(const bf16x8*)(qv_bh + (size_t)arow2 * SD + quad * 8 + 32);

    float lsum[4] = {0.f, 0.f, 0.f, 0.f};
    f32x4 O[4];
#pragma unroll
    for (int dt = 0; dt < 4; ++dt) O[dt] = (f32x4){0.f, 0.f, 0.f, 0.f};

    float  (*Gl)[83] = GP[wave].g;
    ushort (*Pl)[72] = GP[wave].p;

    // stage chunk mc's k (64 rows) + p band (128 rows) into LDS, XOR-swizzled
    auto stage = [&](int mc) {
        const int m0s = mc * 64;
        const int cb  = (mc <= mcD) ? (m0s - n0 + 960) : (m0s - n0 - 65);
#pragma unroll
        for (int it = 0; it < 2; ++it) {
            int t = it * 256 + tid;
            int r = t >> 3, s = t & 7;
            gll16(k_bh + (size_t)(m0s + r) * 64 + ((s ^ (r & 7)) * 8),
                  (char*)Kb + t * 16);
        }
#pragma unroll
        for (int it = 0; it < 4; ++it) {
            int t = it * 256 + tid;
            int r = t >> 3, s = t & 7;
            int c = cb + r; c = (c < 0) ? 0 : (c > SS - 1 ? SS - 1 : c);
            gll16(p_bh + (size_t)c * 64 + ((s ^ (r & 7)) * 8),
                  (char*)Pb + t * 16);
        }
    };

    stage(0);

    for (int mc = 0; mc < 16; ++mc) {
        const int m0 = mc * 64;
        const int diff = m0 - n0;
        const bool lowerband = (mc <= mcD);

        __syncthreads();   // staged data ready (compiler drains vmcnt before barrier)

        // ---- S_u = q_u . k^T from staged Kb ----
        f32x4 S[4];
#pragma unroll
        for (int mt = 0; mt < 4; ++mt) {
            const int r = mt * 16 + l15;
            f32x4 c = (f32x4){0.f, 0.f, 0.f, 0.f};
            c = MFMA16(a_u0, sfrag(Kb, r, quad), c);
            c = MFMA16(a_u1, sfrag(Kb, r, quad + 4), c);
            S[mt] = c;
        }

        // ---- staged band GEMM + diagonal gather via Glds ----
        float sv[4][4];
#pragma unroll
        for (int mt = 0; mt < 4; ++mt)
#pragma unroll
            for (int r = 0; r < 4; ++r) sv[mt][r] = 0.f;

        {
            const bf16x8 av0 = lowerband ? a_vl0 : a_vu0;
            const bf16x8 av1 = lowerband ? a_vl1 : a_vu1;
#pragma unroll
            for (int ti = 0; ti < 5; ++ti) {
                const int t = (3 - wave + ti) * 16 + l15;
                f32x4 g = (f32x4){0.f, 0.f, 0.f, 0.f};
                g = MFMA16(av0, sfrag(Pb, t, quad), g);
                g = MFMA16(av1, sfrag(Pb, t, quad + 4), g);
#pragma unroll
                for (int r = 0; r < 4; ++r)
                    Gl[quad * 4 + r][ti * 16 + l15] = g[r];
            }
#pragma unroll
            for (int mt = 0; mt < 4; ++mt) {
                const int mloc = mt * 16 + l15;
#pragma unroll
                for (int r = 0; r < 4; ++r) {
                    const int q4r = quad * 4 + r;
                    const int d1 = diff + mloc - (wave * 16 + q4r);
                    const bool use = lowerband ? (d1 <= 0) : (d1 >= 2);
                    if (use) sv[mt][r] = Gl[q4r][mloc - q4r + 15];
                }
            }
        }

        // ---- diagonal chunk: upper band direct from global ----
        if (mc == mcD) {
            const int cbase = diff - 65;
            bf16x8 pu0[5], pu1[5];
#pragma unroll
            for (int ti = 0; ti < 5; ++ti) {
                int t = (3 - wave + ti) * 16 + l15;
                int c = cbase + t;
                c = (c < 0) ? 0 : (c > SS - 1 ? SS - 1 : c);
                const ushort* pr = p_bh + (size_t)c * SD + quad * 8;
                pu0[ti] = *(const bf16x8*)pr;
                pu1[ti] = *(const bf16x8*)(pr + 32);
            }
#pragma unroll
            for (int ti = 0; ti < 5; ++ti) {
                f32x4 g = (f32x4){0.f, 0.f, 0.f, 0.f};
                g = MFMA16(a_vu0, pu0[ti], g);
                g = MFMA16(a_vu1, pu1[ti], g);
#pragma unroll
                for (int r = 0; r < 4; ++r)
                    Gl[quad * 4 + r][ti * 16 + l15] = g[r];
            }
#pragma unroll
            for (int mt = 0; mt < 4; ++mt) {
                const int mloc = mt * 16 + l15;
#pragma unroll
                for (int r = 0; r < 4; ++r) {
                    const int q4r = quad * 4 + r;
                    const int d1 = diff + mloc - (wave * 16 + q4r);
                    if (d1 >= 2) sv[mt][r] = Gl[q4r][mloc - q4r + 15];
                }
            }
        }

        __syncthreads();   // all waves done reading Kb/Pb
        if (mc + 1 < 16) stage(mc + 1);   // DMA overlaps exp/PV below

        // ---- v burst (direct, line-aligned chunk-tiled rows) ----
        bf16x8 vb0[4], vb1[4];
#pragma unroll
        for (int dt = 0; dt < 4; ++dt) {
            const ushort* vp = vt_bh + (size_t)(m0 + dt * 16 + l15) * 64 + quad * 8;
            vb0[dt] = *(const bf16x8*)vp;
            vb1[dt] = *(const bf16x8*)(vp + 32);
        }

        // ---- e = exp(logit), lane-local l accumulation ----
        float e[4][4];
#pragma unroll
        for (int mt = 0; mt < 4; ++mt)
#pragma unroll
            for (int r = 0; r < 4; ++r) {
                e[mt][r] = __expf(S[mt][r] + sv[mt][r]);
                lsum[r] += e[mt][r];
            }

        // ---- P: C-layout -> A-layout via LDS (aliases Glds; gather reads
        //      above completed in-order before these writes) ----
#pragma unroll
        for (int mt = 0; mt < 4; ++mt)
#pragma unroll
            for (int r = 0; r < 4; ++r)
                Pl[quad * 4 + r][mt * 16 + l15] = f2b(e[mt][r]);

        // ---- O += P . V ----
        bf16x8 ap0 = *(const bf16x8*)&Pl[l15][quad * 8];
        bf16x8 ap1 = *(const bf16x8*)&Pl[l15][32 + quad * 8];
#pragma unroll
        for (int dt = 0; dt < 4; ++dt) {
            O[dt] = MFMA16(ap0, vb0[dt], O[dt]);
            O[dt] = MFMA16(ap1, vb1[dt], O[dt]);
        }
    }

    // final l reduction across the 16 lanes of each row group
#pragma unroll
    for (int mask = 1; mask <= 8; mask <<= 1)
#pragma unroll
        for (int r = 0; r < 4; ++r)
            lsum[r] += __shfl_xor(lsum[r], mask, 16);

    float inv[4];
#pragma unroll
    for (int r = 0; r < 4; ++r) inv[r] = 1.f / lsum[r];

#pragma unroll
    for (int dt = 0; dt < 4; ++dt)
#pragma unroll
        for (int r = 0; r < 4; ++r) {
            int nn = n0 + wave * 16 + quad * 4 + r;
            ctx[((size_t)b * SS + nn) * (SH * SD) + h * SD + dt * 16 + l15] =
                f2b(O[dt][r] * inv[r]);
        }
}

// ---------------------------------------------------------------------------
// Kernel 3: output projection, bf16 MFMA GEMM.
// ---------------------------------------------------------------------------
__global__ __launch_bounds__(256) void outproj_kernel(
    const ushort* __restrict__ ctx, const ushort* __restrict__ wt,
    float* __restrict__ out)
{
    __shared__ ushort Asm[128 * 32];
    __shared__ ushort Bsm[128 * 32];

    const int tid  = threadIdx.x;
    const int wave = tid >> 6, lane = tid & 63;
    const int quad = lane >> 4, l15 = lane & 15;
    const int row0 = blockIdx.x * 128;
    const int col0 = blockIdx.y * 128;
    const int wr = wave >> 1, wc = wave & 1;

    const ushort* A  = ctx + (size_t)row0 * SDM;
    const ushort* Bw = wt + (size_t)4 * (SDM * SDM) + (size_t)col0 * SDM;

    f32x4 acc[4][4];
#pragma unroll
    for (int i = 0; i < 4; ++i)
#pragma unroll
        for (int j = 0; j < 4; ++j) acc[i][j] = (f32x4){0.f, 0.f, 0.f, 0.f};

    for (int k0 = 0; k0 < SDM; k0 += 32) {
#pragma unroll
        for (int j = 0; j < 2; ++j) {
            int t = j * 256 + tid;
            int r = t >> 2, kp = (t & 3) * 8;
            gll16(A  + (size_t)r * SDM + k0 + kp, (char*)Asm + t * 16);
            gll16(Bw + (size_t)r * SDM + k0 + kp, (char*)Bsm + t * 16);
        }
        __syncthreads();

        bf16x8 af[4], bfr[4];
#pragma unroll
        for (int mt = 0; mt < 4; ++mt)
            af[mt] = *(const bf16x8*)&Asm[(wr * 64 + mt * 16 + l15) * 32 + quad * 8];
#pragma unroll
        for (int nt = 0; nt < 4; ++nt)
            bfr[nt] = *(const bf16x8*)&Bsm[(wc * 64 + nt * 16 + l15) * 32 + quad * 8];
#pragma unroll
        for (int mt = 0; mt < 4; ++mt)
#pragma unroll
            for (int nt = 0; nt < 4; ++nt)
                acc[mt][nt] = MFMA16(af[mt], bfr[nt], acc[mt][nt]);
        __syncthreads();
    }

#pragma unroll
    for (int mt = 0; mt < 4; ++mt)
#pragma unroll
        for (int nt = 0; nt < 4; ++nt) {
            const int R = row0 + wr * 64 + mt * 16 + quad * 4;
            const int C = col0 + wc * 64 + nt * 16 + l15;
#pragma unroll
            for (int r = 0; r < 4; ++r)
                out[(size_t)(R + r) * SDM + C] = acc[mt][nt][r];
        }
}

// ---------------------------------------------------------------------------
extern "C" void kernel_launch(void* const* d_in, const int* in_sizes, int n_in,
                              void* d_out, int out_size, void* d_ws, size_t ws_size,
                              hipStream_t stream)
{
    const float* query  = (const float*)d_in[0];
    const float* key    = (const float*)d_in[1];
    const float* value  = (const float*)d_in[2];
    const float* pos    = (const float*)d_in[3];
    const float* qw     = (const float*)d_in[4];
    const float* kw     = (const float*)d_in[5];
    const float* vw     = (const float*)d_in[6];
    const float* pw     = (const float*)d_in[7];
    const float* projw  = (const float*)d_in[8];
    const float* bias_u = (const float*)d_in[9];
    const float* bias_v = (const float*)d_in[10];

    char* w = (char*)d_ws;
    const size_t MB = 1024 * 1024;
    ushort* xbf = (ushort*)w;                 // 32 MB (dead after projmm)
    ushort* quo = (ushort*)(w + 32 * MB);
    ushort* qvo = (ushort*)(w + 40 * MB);
    ushort* ko  = (ushort*)(w + 48 * MB);
    ushort* po  = (ushort*)(w + 56 * MB);
    ushort* vto = (ushort*)(w + 64 * MB);     // chunk-tiled [bh][mc][d][64]
    ushort* wt  = (ushort*)(w + 72 * MB);     // 2.5 MB
    ushort* ctx = (ushort*)w;                 // aliases dead xbf

    dim3 gcx(2048, 4);
    convert_x_kernel<<<gcx, 256, 0, stream>>>(query, key, value, pos, xbf);
    dim3 gcw(1024, 5);
    convert_w_kernel<<<gcw, 256, 0, stream>>>(qw, kw, vw, pw, projw, wt);

    dim3 g1(64, 4, 4);
    projmm_kernel<<<g1, 256, 0, stream>>>(xbf, wt, bias_u, bias_v,
                                          quo, qvo, ko, po, vto);

    attn_kernel<<<dim3(1024), 256, 0, stream>>>(quo, qvo, ko, po, vto, ctx);

    dim3 g3(64, 4);
    outproj_kernel<<<g3, 256, 0, stream>>>(ctx, wt, (float*)d_out);
}